// Round 1
// baseline (159.487 us; speedup 1.0000x reference)
//
#include <hip/hip_runtime.h>

#define NB 128
#define NS 1024
#define NE 256
#define NR 64
#define NO 1024
#define NK (NE*NR)   // 16384

// ---------------------------------------------------------------------------
// k1: tensor[b][e][r] = sum_{s < len[b]} fillers[b][s][e] * roles[b][s][r]
// grid: NB*4 blocks (batch x e-quarter of 64), 256 threads.
// Each thread owns a 4x4 (e x r) accumulator tile.
// ---------------------------------------------------------------------------
__global__ __launch_bounds__(256) void k1_tensor(
    const float* __restrict__ fillers, const float* __restrict__ roles,
    const int* __restrict__ lengths, float* __restrict__ tensor)
{
    __shared__ float sf[16][64];   // 16 seq rows x 64 filler slice
    __shared__ float sr[16][64];   // 16 seq rows x 64 roles

    const int bid = blockIdx.x;
    const int b   = bid >> 2;
    const int e0  = (bid & 3) << 6;
    const int len = lengths[b];
    const int tid = threadIdx.x;
    const int te  = tid >> 4;   // 0..15 : e-group / staging row
    const int tr  = tid & 15;   // 0..15 : r-group / staging col4

    float acc[4][4] = {};

    const int nch = (len + 15) >> 4;
    for (int c = 0; c < nch; ++c) {
        const int s = (c << 4) + te;
        float4 fv = make_float4(0.f, 0.f, 0.f, 0.f);
        float4 rv = make_float4(0.f, 0.f, 0.f, 0.f);
        if (s < len) {
            fv = *(const float4*)(fillers + (size_t)(b*NS + s)*NE + e0 + tr*4);
            rv = *(const float4*)(roles   + (size_t)(b*NS + s)*NR + tr*4);
        }
        __syncthreads();   // previous iteration's LDS reads done
        *(float4*)&sf[te][tr*4] = fv;
        *(float4*)&sr[te][tr*4] = rv;
        __syncthreads();

        #pragma unroll
        for (int i = 0; i < 16; ++i) {
            const float4 f = *(const float4*)&sf[i][te*4];
            const float4 r = *(const float4*)&sr[i][tr*4];
            float fa[4] = {f.x, f.y, f.z, f.w};
            float ra[4] = {r.x, r.y, r.z, r.w};
            #pragma unroll
            for (int p = 0; p < 4; ++p)
                #pragma unroll
                for (int q = 0; q < 4; ++q)
                    acc[p][q] += fa[p] * ra[q];
        }
    }

    // tensor[b][e0+te*4+p][tr*4+q]
    float* tp = tensor + (size_t)(b*NE + e0 + te*4)*NR + tr*4;
    #pragma unroll
    for (int p = 0; p < 4; ++p) {
        float4 v = make_float4(acc[p][0], acc[p][1], acc[p][2], acc[p][3]);
        *(float4*)(tp + (size_t)p*NR) = v;
    }
}

// ---------------------------------------------------------------------------
// k2: part[kz][b][o] = sum_{k in chunk kz} tensor[b][k] * W[o][k]
// grid: (4 b-tiles of 32) x (16 o-tiles of 64) x (8 k-chunks of 2048), 256 thr
// ---------------------------------------------------------------------------
__global__ __launch_bounds__(256) void k2_partial(
    const float* __restrict__ tensor, const float* __restrict__ W,
    float* __restrict__ part)
{
    __shared__ float Ts[32][36];   // [b][kk], pad to keep float4 alignment
    __shared__ float Wt[32][68];   // [kk][o], transposed W tile

    const int b0  = blockIdx.x << 5;
    const int o0  = blockIdx.y << 6;
    const int kz  = blockIdx.z;
    const int tid = threadIdx.x;
    const int to  = tid & 15;    // o-group (4 outs)
    const int tbg = tid >> 4;    // 0..15 -> 2 b rows
    const int srow = tid >> 3;   // staging row 0..31
    const int scol = tid & 7;    // staging col4 0..7

    float4 a0 = make_float4(0.f, 0.f, 0.f, 0.f);
    float4 a1 = make_float4(0.f, 0.f, 0.f, 0.f);

    const int kbase = kz << 11;
    for (int k = kbase; k < kbase + 2048; k += 32) {
        float4 tv = *(const float4*)(tensor + (size_t)(b0 + srow)*NK + k + scol*4);
        float4 w0 = *(const float4*)(W + (size_t)(o0 + srow     )*NK + k + scol*4);
        float4 w1 = *(const float4*)(W + (size_t)(o0 + srow + 32)*NK + k + scol*4);
        __syncthreads();
        *(float4*)&Ts[srow][scol*4] = tv;
        Wt[scol*4+0][srow] = w0.x;  Wt[scol*4+1][srow] = w0.y;
        Wt[scol*4+2][srow] = w0.z;  Wt[scol*4+3][srow] = w0.w;
        Wt[scol*4+0][srow+32] = w1.x;  Wt[scol*4+1][srow+32] = w1.y;
        Wt[scol*4+2][srow+32] = w1.z;  Wt[scol*4+3][srow+32] = w1.w;
        __syncthreads();

        #pragma unroll
        for (int kk = 0; kk < 32; ++kk) {
            const float4 w = *(const float4*)&Wt[kk][to*4];
            const float t0 = Ts[tbg*2    ][kk];
            const float t1 = Ts[tbg*2 + 1][kk];
            a0.x += t0*w.x; a0.y += t0*w.y; a0.z += t0*w.z; a0.w += t0*w.w;
            a1.x += t1*w.x; a1.y += t1*w.y; a1.z += t1*w.z; a1.w += t1*w.w;
        }
    }

    float* pp = part + ((size_t)kz*NB + b0 + tbg*2)*NO + o0 + to*4;
    *(float4*)pp        = a0;
    *(float4*)(pp + NO) = a1;
}

// ---------------------------------------------------------------------------
// k3: out[b][o] = bias[o] + sum_z part[z][b][o]
// ---------------------------------------------------------------------------
__global__ __launch_bounds__(256) void k3_reduce(
    const float* __restrict__ part, const float* __restrict__ bias,
    float* __restrict__ out)
{
    const int i = blockIdx.x * 256 + threadIdx.x;   // 0 .. NB*NO-1
    float v = bias[i & (NO - 1)];
    #pragma unroll
    for (int z = 0; z < 8; ++z)
        v += part[(size_t)z*NB*NO + i];
    out[i] = v;
}

extern "C" void kernel_launch(void* const* d_in, const int* in_sizes, int n_in,
                              void* d_out, int out_size, void* d_ws, size_t ws_size,
                              hipStream_t stream)
{
    const float* fillers = (const float*)d_in[0];
    const float* roles   = (const float*)d_in[1];
    const int*   lengths = (const int*)d_in[2];
    const float* W       = (const float*)d_in[3];
    const float* bias    = (const float*)d_in[4];
    float* out    = (float*)d_out;
    float* tensor = (float*)d_ws;                      // NB*NK floats (8.4 MB)
    float* part   = tensor + (size_t)NB*NK;            // 8*NB*NO floats (4.2 MB)

    k1_tensor<<<NB*4, 256, 0, stream>>>(fillers, roles, lengths, tensor);
    dim3 g2(4, 16, 8);
    k2_partial<<<g2, 256, 0, stream>>>(tensor, W, part);
    k3_reduce<<<(NB*NO)/256, 256, 0, stream>>>(part, bias, out);
}

// Round 2
// 100.785 us; speedup vs baseline: 1.5824x; 1.5824x over previous
//
#include <hip/hip_runtime.h>
#include <hip/hip_bf16.h>

#define NB 128
#define NS 1024
#define NE 256
#define NR 64
#define NO 1024
#define NK (NE*NR)   // 16384

typedef __attribute__((ext_vector_type(8))) short short8;          // MFMA A/B frag (8 bf16)
typedef __attribute__((ext_vector_type(4))) float float4v;         // MFMA C/D frag
typedef __attribute__((ext_vector_type(4))) unsigned short ushort4v;
typedef __attribute__((ext_vector_type(8))) unsigned short ushort8v;

static __device__ inline unsigned short f2bf(float x) {
    union { float f; unsigned u; } v; v.f = x;
    unsigned r = v.u + 0x7fffu + ((v.u >> 16) & 1u);   // RNE
    return (unsigned short)(r >> 16);
}

// ---------------------------------------------------------------------------
// k1: tensor[b][e][r] = sum_{s < len[b]} fillers[b][s][e] * roles[b][s][r]
// (bf16 output for the MFMA consumer)
// ---------------------------------------------------------------------------
__global__ __launch_bounds__(256) void k1_tensor(
    const float* __restrict__ fillers, const float* __restrict__ roles,
    const int* __restrict__ lengths, unsigned short* __restrict__ tensor)
{
    __shared__ float sf[16][64];
    __shared__ float sr[16][64];

    const int bid = blockIdx.x;
    const int b   = bid >> 2;
    const int e0  = (bid & 3) << 6;
    const int len = lengths[b];
    const int tid = threadIdx.x;
    const int te  = tid >> 4;
    const int tr  = tid & 15;

    float acc[4][4] = {};

    const int nch = (len + 15) >> 4;
    for (int c = 0; c < nch; ++c) {
        const int s = (c << 4) + te;
        float4 fv = make_float4(0.f, 0.f, 0.f, 0.f);
        float4 rv = make_float4(0.f, 0.f, 0.f, 0.f);
        if (s < len) {
            fv = *(const float4*)(fillers + (size_t)(b*NS + s)*NE + e0 + tr*4);
            rv = *(const float4*)(roles   + (size_t)(b*NS + s)*NR + tr*4);
        }
        __syncthreads();
        *(float4*)&sf[te][tr*4] = fv;
        *(float4*)&sr[te][tr*4] = rv;
        __syncthreads();

        #pragma unroll
        for (int i = 0; i < 16; ++i) {
            const float4 f = *(const float4*)&sf[i][te*4];
            const float4 r = *(const float4*)&sr[i][tr*4];
            float fa[4] = {f.x, f.y, f.z, f.w};
            float ra[4] = {r.x, r.y, r.z, r.w};
            #pragma unroll
            for (int p = 0; p < 4; ++p)
                #pragma unroll
                for (int q = 0; q < 4; ++q)
                    acc[p][q] += fa[p] * ra[q];
        }
    }

    unsigned short* tp = tensor + (size_t)(b*NE + e0 + te*4)*NR + tr*4;
    #pragma unroll
    for (int p = 0; p < 4; ++p) {
        ushort4v v = { f2bf(acc[p][0]), f2bf(acc[p][1]), f2bf(acc[p][2]), f2bf(acc[p][3]) };
        *(ushort4v*)(tp + (size_t)p*NR) = v;
    }
}

// ---------------------------------------------------------------------------
// k2: MFMA bf16 split-K GEMM: part[kz][b][o] = sum_{k in chunk} T[b][k]*W[o][k]
// tile BM=64 x BN=64, BK=128, KSPLIT=16 (chunk 1024). grid (2,16,16), 256 thr.
// 4 waves, each owns a 32x32 sub-tile = 2x2 fragments of 16x16x32.
// ---------------------------------------------------------------------------
#define BM 64
#define BN 64
#define BK 128
#define KSPLIT 16
#define KC (NK/KSPLIT)   // 1024

__global__ __launch_bounds__(256) void k2_mfma(
    const unsigned short* __restrict__ A,   // tensor bf16 [NB][NK]
    const float* __restrict__ W,            // [NO][NK]
    float* __restrict__ part)               // [KSPLIT][NB][NO]
{
    __shared__ unsigned short As[BM * BK];  // 16 KB, XOR-swizzled rows (256 B stride)
    __shared__ unsigned short Bs[BN * BK];  // 16 KB

    const int m0   = blockIdx.x * BM;
    const int o0   = blockIdx.y * BN;
    const int kz   = blockIdx.z;
    const int tid  = threadIdx.x;
    const int lane = tid & 63;
    const int wid  = tid >> 6;
    const int wm   = wid >> 1;          // 0..1: which 32-row half
    const int wn   = wid & 1;           // 0..1: which 32-col half
    const int lrow = lane & 15;
    const int lgrp = lane >> 4;         // 0..3

    float4v acc[2][2];
    #pragma unroll
    for (int i = 0; i < 2; ++i)
        #pragma unroll
        for (int j = 0; j < 2; ++j)
            acc[i][j] = (float4v){0.f, 0.f, 0.f, 0.f};

    for (int step = 0; step < KC / BK; ++step) {
        const int kb = kz * KC + step * BK;

        // ---- global -> regs (A: 4x16B bf16, B: 8x float4 fp32) ----
        ushort8v av[4];
        #pragma unroll
        for (int i = 0; i < 4; ++i) {
            const int c = tid + 256 * i;          // chunk id
            const int r = c >> 4, c16 = c & 15;
            av[i] = *(const ushort8v*)(A + (size_t)(m0 + r)*NK + kb + c16*8);
        }
        float4 wv[8];
        #pragma unroll
        for (int i = 0; i < 8; ++i) {
            const int c = tid + 256 * i;
            const int r = c >> 5, c4 = c & 31;
            wv[i] = *(const float4*)(W + (size_t)(o0 + r)*NK + kb + c4*4);
        }

        __syncthreads();   // previous iteration's LDS reads complete

        // ---- regs -> LDS (swizzled) ----
        #pragma unroll
        for (int i = 0; i < 4; ++i) {
            const int c = tid + 256 * i;
            const int r = c >> 4, c16 = c & 15;
            const int byte = (r*256 + c16*16) ^ ((r & 7) << 4);
            *(ushort8v*)((char*)As + byte) = av[i];
        }
        #pragma unroll
        for (int i = 0; i < 8; ++i) {
            const int c = tid + 256 * i;
            const int r = c >> 5, c4 = c & 31;
            ushort4v bv = { f2bf(wv[i].x), f2bf(wv[i].y), f2bf(wv[i].z), f2bf(wv[i].w) };
            const int byte = (r*256 + c4*8) ^ ((r & 7) << 4);
            *(ushort4v*)((char*)Bs + byte) = bv;
        }

        __syncthreads();

        // ---- MFMA over BK ----
        #pragma unroll
        for (int kk = 0; kk < BK; kk += 32) {
            short8 af[2], bf[2];
            #pragma unroll
            for (int mf = 0; mf < 2; ++mf) {
                const int r = wm*32 + mf*16 + lrow;
                const int byte = (r*256 + (kk + lgrp*8)*2) ^ ((r & 7) << 4);
                af[mf] = *(const short8*)((const char*)As + byte);
            }
            #pragma unroll
            for (int nf = 0; nf < 2; ++nf) {
                const int r = wn*32 + nf*16 + lrow;
                const int byte = (r*256 + (kk + lgrp*8)*2) ^ ((r & 7) << 4);
                bf[nf] = *(const short8*)((const char*)Bs + byte);
            }
            #pragma unroll
            for (int mf = 0; mf < 2; ++mf)
                #pragma unroll
                for (int nf = 0; nf < 2; ++nf)
                    acc[mf][nf] = __builtin_amdgcn_mfma_f32_16x16x32_bf16(
                        af[mf], bf[nf], acc[mf][nf], 0, 0, 0);
        }
    }

    // ---- epilogue: C/D layout col=lane&15, row=(lane>>4)*4+reg ----
    float* pbase = part + (size_t)kz * NB * NO;
    #pragma unroll
    for (int mf = 0; mf < 2; ++mf) {
        #pragma unroll
        for (int nf = 0; nf < 2; ++nf) {
            const int o = o0 + wn*32 + nf*16 + lrow;
            #pragma unroll
            for (int reg = 0; reg < 4; ++reg) {
                const int m = m0 + wm*32 + mf*16 + lgrp*4 + reg;
                pbase[(size_t)m * NO + o] = acc[mf][nf][reg];
            }
        }
    }
}

// ---------------------------------------------------------------------------
// k3: out[b][o] = bias[o] + sum_z part[z][b][o]   (float4, 128 blocks)
// ---------------------------------------------------------------------------
__global__ __launch_bounds__(256) void k3_reduce(
    const float* __restrict__ part, const float* __restrict__ bias,
    float* __restrict__ out)
{
    const int i = (blockIdx.x * 256 + threadIdx.x) * 4;
    float4 v = *(const float4*)(bias + (i & (NO - 1)));
    #pragma unroll
    for (int z = 0; z < KSPLIT; ++z) {
        float4 p = *(const float4*)(part + (size_t)z*NB*NO + i);
        v.x += p.x; v.y += p.y; v.z += p.z; v.w += p.w;
    }
    *(float4*)(out + i) = v;
}

extern "C" void kernel_launch(void* const* d_in, const int* in_sizes, int n_in,
                              void* d_out, int out_size, void* d_ws, size_t ws_size,
                              hipStream_t stream)
{
    const float* fillers = (const float*)d_in[0];
    const float* roles   = (const float*)d_in[1];
    const int*   lengths = (const int*)d_in[2];
    const float* W       = (const float*)d_in[3];
    const float* bias    = (const float*)d_in[4];
    float* out = (float*)d_out;

    unsigned short* tensor = (unsigned short*)d_ws;                 // NB*NK bf16 = 4.19 MB
    float* part = (float*)((char*)d_ws + (size_t)NB*NK*2);          // 16*NB*NO f32 = 8.39 MB

    k1_tensor<<<NB*4, 256, 0, stream>>>(fillers, roles, lengths, tensor);
    dim3 g2(NB/BM, NO/BN, KSPLIT);   // (2, 16, 16)
    k2_mfma<<<g2, 256, 0, stream>>>(tensor, W, part);
    k3_reduce<<<(NB*NO)/1024, 256, 0, stream>>>(part, bias, out);
}

// Round 3
// 77.126 us; speedup vs baseline: 2.0679x; 1.3068x over previous
//
#include <hip/hip_runtime.h>
#include <hip/hip_bf16.h>

#define NB 128
#define NS 1024
#define NE 256
#define NR 64
#define NO 1024
#define NK (NE*NR)   // 16384

typedef __attribute__((ext_vector_type(8))) short short8;          // MFMA A/B frag (8 bf16)
typedef __attribute__((ext_vector_type(4))) float float4v;         // MFMA C/D frag
typedef __attribute__((ext_vector_type(4))) unsigned short ushort4v;
typedef __attribute__((ext_vector_type(8))) unsigned short ushort8v;
typedef __attribute__((ext_vector_type(4))) unsigned int uint4v;

static __device__ inline unsigned short f2bf(float x) {
    union { float f; unsigned u; } v; v.f = x;
    unsigned r = v.u + 0x7fffu + ((v.u >> 16) & 1u);   // RNE
    return (unsigned short)(r >> 16);
}
static __device__ inline unsigned pack2(float lo, float hi) {
    return (unsigned)f2bf(lo) | ((unsigned)f2bf(hi) << 16);
}
static __device__ inline float bf2f(unsigned short h) {
    union { unsigned u; float f; } v; v.u = ((unsigned)h) << 16;
    return v.f;
}

// ---------------------------------------------------------------------------
// k1: MFMA partial tensor: parts[ch][b][e][r] = sum_{s in chunk, s<len} F[b][s][e]*R[b][s][r]
// grid 512 = 128 batches x 4 s-chunks of 256, 512 threads (8 waves).
// Wave w owns 32(e) x 64(r) = 2x4 fragments of 16x16x32 (K = s).
// LDS layout: [s-pair q][e] packed u32 (bf16 s | bf16 s+1 <<16) -> staging
// writes are contiguous uint4; fragment reads are 4x b32 at 2-way aliasing.
// ---------------------------------------------------------------------------
#define SCH 256
#define NCH 4
#define KST 32
#define SA 260   // A row stride in u32 (256 e + 4 pad)
#define SB 68    // B row stride in u32 (64 r + 4 pad)

__global__ __launch_bounds__(512) void k1_mfma(
    const float* __restrict__ fillers, const float* __restrict__ roles,
    const int* __restrict__ lengths, unsigned short* __restrict__ parts)
{
    __shared__ unsigned As32[16 * SA];   // 16.6 KB
    __shared__ unsigned Bs32[16 * SB];   // 4.4 KB

    const int bid = blockIdx.x;
    const int b   = bid >> 2;
    const int ch  = bid & 3;
    const int len = lengths[b];
    const int start = ch * SCH;
    const int end   = min(len, start + SCH);
    const int tid   = threadIdx.x;

    unsigned short* pp = parts + (size_t)(ch * NB + b) * NK;

    if (end <= start) {   // nothing to accumulate: write zero partial (32 KB)
        ushort8v z = {0,0,0,0,0,0,0,0};
        #pragma unroll
        for (int i = 0; i < 4; ++i)
            *(ushort8v*)(pp + tid * 32 + i * 8) = z;
        return;
    }

    const int lane = tid & 63;
    const int w    = tid >> 6;        // wave 0..7
    const int lrow = lane & 15;
    const int lgrp = lane >> 4;       // 0..3
    const int e4   = tid & 63;        // A staging: e-group (4 e's)
    const int qa   = tid >> 6;        // A staging: 0..7
    const int qb   = tid >> 4;        // B staging: 0..15 (tid<256)
    const int r4   = tid & 15;        // B staging: r-group

    float4v acc[2][4];
    #pragma unroll
    for (int i = 0; i < 2; ++i)
        #pragma unroll
        for (int j = 0; j < 4; ++j)
            acc[i][j] = (float4v){0.f, 0.f, 0.f, 0.f};

    const float4 zf4 = make_float4(0.f, 0.f, 0.f, 0.f);
    float4 av[2][2];   // [j][s / s+1]
    float4 bv[2];

    const int nsteps = (end - start + KST - 1) / KST;

    // ---- prologue load (step 0) ----
    {
        const int s0 = start;
        #pragma unroll
        for (int j = 0; j < 2; ++j) {
            const int s = s0 + 2 * (j * 8 + qa);
            const float* fp = fillers + ((size_t)b * NS + s) * NE + e4 * 4;
            av[j][0] = (s     < end) ? *(const float4*)fp          : zf4;
            av[j][1] = (s + 1 < end) ? *(const float4*)(fp + NE)   : zf4;
        }
        if (tid < 256) {
            const int s = s0 + 2 * qb;
            const float* rp = roles + ((size_t)b * NS + s) * NR + r4 * 4;
            bv[0] = (s     < end) ? *(const float4*)rp          : zf4;
            bv[1] = (s + 1 < end) ? *(const float4*)(rp + NR)   : zf4;
        }
    }

    for (int step = 0; step < nsteps; ++step) {
        __syncthreads();   // previous step's LDS reads complete

        // ---- regs -> LDS (packed bf16 pairs, contiguous uint4 writes) ----
        #pragma unroll
        for (int j = 0; j < 2; ++j) {
            const int q = j * 8 + qa;
            uint4v p;
            p.x = pack2(av[j][0].x, av[j][1].x);
            p.y = pack2(av[j][0].y, av[j][1].y);
            p.z = pack2(av[j][0].z, av[j][1].z);
            p.w = pack2(av[j][0].w, av[j][1].w);
            *(uint4v*)&As32[q * SA + e4 * 4] = p;
        }
        if (tid < 256) {
            uint4v p;
            p.x = pack2(bv[0].x, bv[1].x);
            p.y = pack2(bv[0].y, bv[1].y);
            p.z = pack2(bv[0].z, bv[1].z);
            p.w = pack2(bv[0].w, bv[1].w);
            *(uint4v*)&Bs32[qb * SB + r4 * 4] = p;
        }

        __syncthreads();

        // ---- prefetch next step while MFMAing this one ----
        if (step + 1 < nsteps) {
            const int s0 = start + (step + 1) * KST;
            #pragma unroll
            for (int j = 0; j < 2; ++j) {
                const int s = s0 + 2 * (j * 8 + qa);
                const float* fp = fillers + ((size_t)b * NS + s) * NE + e4 * 4;
                av[j][0] = (s     < end) ? *(const float4*)fp          : zf4;
                av[j][1] = (s + 1 < end) ? *(const float4*)(fp + NE)   : zf4;
            }
            if (tid < 256) {
                const int s = s0 + 2 * qb;
                const float* rp = roles + ((size_t)b * NS + s) * NR + r4 * 4;
                bv[0] = (s     < end) ? *(const float4*)rp          : zf4;
                bv[1] = (s + 1 < end) ? *(const float4*)(rp + NR)   : zf4;
            }
        }

        // ---- MFMA: wave tile 32e x 64r, K=32 ----
        short8 af[2];
        #pragma unroll
        for (int mf = 0; mf < 2; ++mf) {
            const int e = w * 32 + mf * 16 + lrow;
            union { unsigned u[4]; short8 s; } t;
            #pragma unroll
            for (int jj = 0; jj < 4; ++jj)
                t.u[jj] = As32[(lgrp * 4 + jj) * SA + e];
            af[mf] = t.s;
        }
        #pragma unroll
        for (int nf = 0; nf < 4; ++nf) {
            const int r = nf * 16 + lrow;
            union { unsigned u[4]; short8 s; } t;
            #pragma unroll
            for (int jj = 0; jj < 4; ++jj)
                t.u[jj] = Bs32[(lgrp * 4 + jj) * SB + r];
            const short8 bfr = t.s;
            #pragma unroll
            for (int mf = 0; mf < 2; ++mf)
                acc[mf][nf] = __builtin_amdgcn_mfma_f32_16x16x32_bf16(
                    af[mf], bfr, acc[mf][nf], 0, 0, 0);
        }
    }

    // ---- epilogue: C/D layout col=lane&15, row=(lane>>4)*4+reg ----
    #pragma unroll
    for (int mf = 0; mf < 2; ++mf) {
        #pragma unroll
        for (int nf = 0; nf < 4; ++nf) {
            const int r = nf * 16 + lrow;
            #pragma unroll
            for (int reg = 0; reg < 4; ++reg) {
                const int e = w * 32 + mf * 16 + lgrp * 4 + reg;
                pp[(size_t)e * NR + r] = f2bf(acc[mf][nf][reg]);
            }
        }
    }
}

// ---------------------------------------------------------------------------
// k1b: tensor[i] = bf16( sum_ch parts[ch][i] )   (8 bf16 per thread)
// ---------------------------------------------------------------------------
__global__ __launch_bounds__(256) void k1b_reduce(
    const unsigned short* __restrict__ parts, unsigned short* __restrict__ tensor)
{
    const size_t i = ((size_t)blockIdx.x * 256 + threadIdx.x) * 8;
    float s[8] = {0.f,0.f,0.f,0.f,0.f,0.f,0.f,0.f};
    #pragma unroll
    for (int ch = 0; ch < NCH; ++ch) {
        ushort8v v = *(const ushort8v*)(parts + (size_t)ch * NB * NK + i);
        #pragma unroll
        for (int j = 0; j < 8; ++j)
            s[j] += bf2f(v[j]);
    }
    ushort8v o;
    #pragma unroll
    for (int j = 0; j < 8; ++j)
        o[j] = f2bf(s[j]);
    *(ushort8v*)(tensor + i) = o;
}

// ---------------------------------------------------------------------------
// k2: MFMA bf16 split-K GEMM: part[kz][b][o] = sum_{k in chunk} T[b][k]*W[o][k]
// ---------------------------------------------------------------------------
#define BM 64
#define BN 64
#define BK 128
#define KSPLIT 16
#define KC (NK/KSPLIT)   // 1024

__global__ __launch_bounds__(256) void k2_mfma(
    const unsigned short* __restrict__ A,   // tensor bf16 [NB][NK]
    const float* __restrict__ W,            // [NO][NK]
    float* __restrict__ part)               // [KSPLIT][NB][NO]
{
    __shared__ unsigned short As[BM * BK];
    __shared__ unsigned short Bs[BN * BK];

    const int m0   = blockIdx.x * BM;
    const int o0   = blockIdx.y * BN;
    const int kz   = blockIdx.z;
    const int tid  = threadIdx.x;
    const int lane = tid & 63;
    const int wid  = tid >> 6;
    const int wm   = wid >> 1;
    const int wn   = wid & 1;
    const int lrow = lane & 15;
    const int lgrp = lane >> 4;

    float4v acc[2][2];
    #pragma unroll
    for (int i = 0; i < 2; ++i)
        #pragma unroll
        for (int j = 0; j < 2; ++j)
            acc[i][j] = (float4v){0.f, 0.f, 0.f, 0.f};

    for (int step = 0; step < KC / BK; ++step) {
        const int kb = kz * KC + step * BK;

        ushort8v av[4];
        #pragma unroll
        for (int i = 0; i < 4; ++i) {
            const int c = tid + 256 * i;
            const int r = c >> 4, c16 = c & 15;
            av[i] = *(const ushort8v*)(A + (size_t)(m0 + r)*NK + kb + c16*8);
        }
        float4 wv[8];
        #pragma unroll
        for (int i = 0; i < 8; ++i) {
            const int c = tid + 256 * i;
            const int r = c >> 5, c4 = c & 31;
            wv[i] = *(const float4*)(W + (size_t)(o0 + r)*NK + kb + c4*4);
        }

        __syncthreads();

        #pragma unroll
        for (int i = 0; i < 4; ++i) {
            const int c = tid + 256 * i;
            const int r = c >> 4, c16 = c & 15;
            const int byte = (r*256 + c16*16) ^ ((r & 7) << 4);
            *(ushort8v*)((char*)As + byte) = av[i];
        }
        #pragma unroll
        for (int i = 0; i < 8; ++i) {
            const int c = tid + 256 * i;
            const int r = c >> 5, c4 = c & 31;
            ushort4v bv = { f2bf(wv[i].x), f2bf(wv[i].y), f2bf(wv[i].z), f2bf(wv[i].w) };
            const int byte = (r*256 + c4*8) ^ ((r & 7) << 4);
            *(ushort4v*)((char*)Bs + byte) = bv;
        }

        __syncthreads();

        #pragma unroll
        for (int kk = 0; kk < BK; kk += 32) {
            short8 af[2], bf[2];
            #pragma unroll
            for (int mf = 0; mf < 2; ++mf) {
                const int r = wm*32 + mf*16 + lrow;
                const int byte = (r*256 + (kk + lgrp*8)*2) ^ ((r & 7) << 4);
                af[mf] = *(const short8*)((const char*)As + byte);
            }
            #pragma unroll
            for (int nf = 0; nf < 2; ++nf) {
                const int r = wn*32 + nf*16 + lrow;
                const int byte = (r*256 + (kk + lgrp*8)*2) ^ ((r & 7) << 4);
                bf[nf] = *(const short8*)((const char*)Bs + byte);
            }
            #pragma unroll
            for (int mf = 0; mf < 2; ++mf)
                #pragma unroll
                for (int nf = 0; nf < 2; ++nf)
                    acc[mf][nf] = __builtin_amdgcn_mfma_f32_16x16x32_bf16(
                        af[mf], bf[nf], acc[mf][nf], 0, 0, 0);
        }
    }

    float* pbase = part + (size_t)kz * NB * NO;
    #pragma unroll
    for (int mf = 0; mf < 2; ++mf) {
        #pragma unroll
        for (int nf = 0; nf < 2; ++nf) {
            const int o = o0 + wn*32 + nf*16 + lrow;
            #pragma unroll
            for (int reg = 0; reg < 4; ++reg) {
                const int m = m0 + wm*32 + mf*16 + lgrp*4 + reg;
                pbase[(size_t)m * NO + o] = acc[mf][nf][reg];
            }
        }
    }
}

// ---------------------------------------------------------------------------
// k3: out[b][o] = bias[o] + sum_z part[z][b][o]
// ---------------------------------------------------------------------------
__global__ __launch_bounds__(256) void k3_reduce(
    const float* __restrict__ part, const float* __restrict__ bias,
    float* __restrict__ out)
{
    const int i = (blockIdx.x * 256 + threadIdx.x) * 4;
    float4 v = *(const float4*)(bias + (i & (NO - 1)));
    #pragma unroll
    for (int z = 0; z < KSPLIT; ++z) {
        float4 p = *(const float4*)(part + (size_t)z*NB*NO + i);
        v.x += p.x; v.y += p.y; v.z += p.z; v.w += p.w;
    }
    *(float4*)(out + i) = v;
}

extern "C" void kernel_launch(void* const* d_in, const int* in_sizes, int n_in,
                              void* d_out, int out_size, void* d_ws, size_t ws_size,
                              hipStream_t stream)
{
    const float* fillers = (const float*)d_in[0];
    const float* roles   = (const float*)d_in[1];
    const int*   lengths = (const int*)d_in[2];
    const float* W       = (const float*)d_in[3];
    const float* bias    = (const float*)d_in[4];
    float* out = (float*)d_out;

    // ws layout: [tensor bf16 4.19MB][ parts bf16 16.8MB == overlaid part f32 8.4MB ]
    unsigned short* tensor = (unsigned short*)d_ws;
    unsigned short* parts  = tensor + (size_t)NB * NK;           // k1 out, k1b in
    float*          part   = (float*)parts;                      // k2 out, k3 in (overlay, disjoint lifetime)

    k1_mfma<<<NB * NCH, 512, 0, stream>>>(fillers, roles, lengths, parts);
    k1b_reduce<<<(NB * NK / 8) / 256, 256, 0, stream>>>(parts, tensor);
    dim3 g2(NB / BM, NO / BN, KSPLIT);   // (2, 16, 16)
    k2_mfma<<<g2, 256, 0, stream>>>(tensor, W, part);
    k3_reduce<<<(NB * NO) / 1024, 256, 0, stream>>>(part, bias, out);
}

// Round 4
// 71.778 us; speedup vs baseline: 2.2220x; 1.0745x over previous
//
#include <hip/hip_runtime.h>
#include <hip/hip_bf16.h>

#define NB 128
#define NS 1024
#define NE 256
#define NR 64
#define NO 1024
#define NK (NE*NR)   // 16384

typedef __attribute__((ext_vector_type(8))) short short8;          // MFMA A/B frag (8 bf16)
typedef __attribute__((ext_vector_type(4))) float float4v;         // MFMA C/D frag
typedef __attribute__((ext_vector_type(4))) unsigned short ushort4v;
typedef __attribute__((ext_vector_type(8))) unsigned short ushort8v;
typedef __attribute__((ext_vector_type(4))) unsigned int uint4v;

static __device__ inline unsigned short f2bf(float x) {
    union { float f; unsigned u; } v; v.f = x;
    unsigned r = v.u + 0x7fffu + ((v.u >> 16) & 1u);   // RNE
    return (unsigned short)(r >> 16);
}
static __device__ inline unsigned pack2(float lo, float hi) {
    return (unsigned)f2bf(lo) | ((unsigned)f2bf(hi) << 16);
}
static __device__ inline float bf2f(unsigned short h) {
    union { unsigned u; float f; } v; v.u = ((unsigned)h) << 16;
    return v.f;
}

// ---------------------------------------------------------------------------
// k1: parts[ch][b][e][r] = sum_{s-pairs p == ch (mod 4), s<len} F[b][s][e]*R[b][s][r]
// grid = NB * 2(e-half) * 4(s-chunk) = 1024 blocks, 512 threads (8 waves).
// Interleaved pair-chunking -> all 4 chunk-siblings do the same step count.
// Block tile: 128 e x 64 r; wave (we 0..3, wn 0..1) owns 32e x 32r = 2x2 frags.
// LDS: [pair q][e or r] packed u32 (bf16 s | bf16 s+1).
// ---------------------------------------------------------------------------
#define NCH 4
#define SA2 132   // A row stride in u32 (128 e + 4 pad)
#define SB2 68    // B row stride in u32 (64 r + 4 pad)

__global__ __launch_bounds__(512) void k1_mfma(
    const float* __restrict__ fillers, const float* __restrict__ roles,
    const int* __restrict__ lengths, unsigned short* __restrict__ parts)
{
    __shared__ unsigned As32[16 * SA2];   // 8.25 KB
    __shared__ unsigned Bs32[16 * SB2];   // 4.25 KB

    const int bid = blockIdx.x;
    const int b   = bid >> 3;
    const int eh  = (bid >> 2) & 1;
    const int ch  = bid & 3;
    const int len = lengths[b];
    const int tid = threadIdx.x;

    const int lane = tid & 63;
    const int wid  = tid >> 6;
    const int lrow = lane & 15;
    const int lgrp = lane >> 4;
    const int we   = wid >> 1;     // 0..3 : 32-e group
    const int wn   = wid & 1;      // 0..1 : 32-r group
    const int qa   = tid >> 5;     // 0..15 : A staging pair
    const int e4a  = tid & 31;     // A staging e-group of 4
    const int qb   = tid >> 4;     // 0..15 : B staging pair (tid<256)
    const int r4   = tid & 15;     // B staging r-group of 4

    // pairs p = ch + 4*k, p < P, P = ceil(len/2); steps of 16 pairs
    const int P      = (len + 1) >> 1;
    const int count  = (P > ch) ? ((P - ch + 3) >> 2) : 0;
    const int nsteps = (count + 15) >> 4;

    float4v acc[2][2];
    #pragma unroll
    for (int i = 0; i < 2; ++i)
        #pragma unroll
        for (int j = 0; j < 2; ++j)
            acc[i][j] = (float4v){0.f, 0.f, 0.f, 0.f};

    const float4 zf4 = make_float4(0.f, 0.f, 0.f, 0.f);
    const float* fbase = fillers + (size_t)b * NS * NE + eh * 128;
    const float* rbase = roles   + (size_t)b * NS * NR;

    float4 av0 = zf4, av1 = zf4, bv0 = zf4, bv1 = zf4;

    // ---- prologue load (step 0) ----
    {
        const int p = ch + 4 * qa;
        const int s = 2 * p;
        const float* fp = fbase + (size_t)s * NE + e4a * 4;
        av0 = (s     < len) ? *(const float4*)fp        : zf4;
        av1 = (s + 1 < len) ? *(const float4*)(fp + NE) : zf4;
        if (tid < 256) {
            const int pB = ch + 4 * qb;
            const int sB = 2 * pB;
            const float* rp = rbase + (size_t)sB * NR + r4 * 4;
            bv0 = (sB     < len) ? *(const float4*)rp        : zf4;
            bv1 = (sB + 1 < len) ? *(const float4*)(rp + NR) : zf4;
        }
    }

    for (int step = 0; step < nsteps; ++step) {
        __syncthreads();   // previous step's LDS reads complete

        {   // regs -> LDS (packed bf16 pairs, contiguous uint4)
            uint4v pk;
            pk.x = pack2(av0.x, av1.x);
            pk.y = pack2(av0.y, av1.y);
            pk.z = pack2(av0.z, av1.z);
            pk.w = pack2(av0.w, av1.w);
            *(uint4v*)&As32[qa * SA2 + e4a * 4] = pk;
            if (tid < 256) {
                uint4v pb;
                pb.x = pack2(bv0.x, bv1.x);
                pb.y = pack2(bv0.y, bv1.y);
                pb.z = pack2(bv0.z, bv1.z);
                pb.w = pack2(bv0.w, bv1.w);
                *(uint4v*)&Bs32[qb * SB2 + r4 * 4] = pb;
            }
        }

        __syncthreads();

        // ---- prefetch next step ----
        if (step + 1 < nsteps) {
            const int p = ch + 4 * ((step + 1) * 16 + qa);
            const int s = 2 * p;
            const float* fp = fbase + (size_t)s * NE + e4a * 4;
            av0 = (s     < len) ? *(const float4*)fp        : zf4;
            av1 = (s + 1 < len) ? *(const float4*)(fp + NE) : zf4;
            if (tid < 256) {
                const int pB = ch + 4 * ((step + 1) * 16 + qb);
                const int sB = 2 * pB;
                const float* rp = rbase + (size_t)sB * NR + r4 * 4;
                bv0 = (sB     < len) ? *(const float4*)rp        : zf4;
                bv1 = (sB + 1 < len) ? *(const float4*)(rp + NR) : zf4;
            }
        }

        // ---- MFMA: 32e x 32r per wave, K=32 ----
        short8 af[2];
        #pragma unroll
        for (int mf = 0; mf < 2; ++mf) {
            const int e = we * 32 + mf * 16 + lrow;
            union { unsigned u[4]; short8 s; } t;
            #pragma unroll
            for (int jj = 0; jj < 4; ++jj)
                t.u[jj] = As32[(lgrp * 4 + jj) * SA2 + e];
            af[mf] = t.s;
        }
        #pragma unroll
        for (int nf = 0; nf < 2; ++nf) {
            const int r = wn * 32 + nf * 16 + lrow;
            union { unsigned u[4]; short8 s; } t;
            #pragma unroll
            for (int jj = 0; jj < 4; ++jj)
                t.u[jj] = Bs32[(lgrp * 4 + jj) * SB2 + r];
            const short8 bfr = t.s;
            #pragma unroll
            for (int mf = 0; mf < 2; ++mf)
                acc[mf][nf] = __builtin_amdgcn_mfma_f32_16x16x32_bf16(
                    af[mf], bfr, acc[mf][nf], 0, 0, 0);
        }
    }

    // ---- epilogue (acc==0 path also writes, covering empty chunks) ----
    unsigned short* pp = parts + (size_t)(ch * NB + b) * NK;
    #pragma unroll
    for (int mf = 0; mf < 2; ++mf) {
        #pragma unroll
        for (int nf = 0; nf < 2; ++nf) {
            const int r = wn * 32 + nf * 16 + lrow;
            #pragma unroll
            for (int reg = 0; reg < 4; ++reg) {
                const int e = eh * 128 + we * 32 + mf * 16 + lgrp * 4 + reg;
                pp[(size_t)e * NR + r] = f2bf(acc[mf][nf][reg]);
            }
        }
    }
}

// ---------------------------------------------------------------------------
// k1b: tensor[i] = bf16( sum_ch parts[ch][i] )
// ---------------------------------------------------------------------------
__global__ __launch_bounds__(256) void k1b_reduce(
    const unsigned short* __restrict__ parts, unsigned short* __restrict__ tensor)
{
    const size_t i = ((size_t)blockIdx.x * 256 + threadIdx.x) * 8;
    float s[8] = {0.f,0.f,0.f,0.f,0.f,0.f,0.f,0.f};
    #pragma unroll
    for (int ch = 0; ch < NCH; ++ch) {
        ushort8v v = *(const ushort8v*)(parts + (size_t)ch * NB * NK + i);
        #pragma unroll
        for (int j = 0; j < 8; ++j)
            s[j] += bf2f(v[j]);
    }
    ushort8v o;
    #pragma unroll
    for (int j = 0; j < 8; ++j)
        o[j] = f2bf(s[j]);
    *(ushort8v*)(tensor + i) = o;
}

// ---------------------------------------------------------------------------
// k2: part[kz][b][o] = sum_{k in chunk kz} T[b][k] * W[o][k]
// BM = 128 (= NB, so W is read exactly once), BN = 64, BK = 128, KSPLIT = 32.
// grid (16 o-tiles, 32 kz), 512 threads; wave (wm 0..3, wn 0..1): 32m x 32o.
// ---------------------------------------------------------------------------
#define BN2 64
#define BK2 128
#define KSPLIT 32
#define KC2 (NK/KSPLIT)   // 512

__global__ __launch_bounds__(512) void k2_mfma(
    const unsigned short* __restrict__ A,   // tensor bf16 [NB][NK]
    const float* __restrict__ W,            // [NO][NK]
    float* __restrict__ part)               // [KSPLIT][NB][NO]
{
    __shared__ unsigned short As[128 * BK2];  // 32 KB, XOR-swizzled 256B rows
    __shared__ unsigned short Bs[BN2 * BK2];  // 16 KB

    const int o0   = blockIdx.x * BN2;
    const int kz   = blockIdx.y;
    const int tid  = threadIdx.x;
    const int lane = tid & 63;
    const int wid  = tid >> 6;
    const int wm   = wid >> 1;   // 0..3
    const int wn   = wid & 1;    // 0..1
    const int lrow = lane & 15;
    const int lgrp = lane >> 4;

    float4v acc[2][2];
    #pragma unroll
    for (int i = 0; i < 2; ++i)
        #pragma unroll
        for (int j = 0; j < 2; ++j)
            acc[i][j] = (float4v){0.f, 0.f, 0.f, 0.f};

    for (int step = 0; step < KC2 / BK2; ++step) {   // 4
        const int kb = kz * KC2 + step * BK2;

        ushort8v av[4];
        #pragma unroll
        for (int i = 0; i < 4; ++i) {
            const int c = tid + 512 * i;           // 0..2047
            const int r = c >> 4, c16 = c & 15;    // r 0..127
            av[i] = *(const ushort8v*)(A + (size_t)r * NK + kb + c16 * 8);
        }
        float4 wv[4];
        #pragma unroll
        for (int i = 0; i < 4; ++i) {
            const int c = tid + 512 * i;
            const int r = c >> 5, c4 = c & 31;     // r 0..63
            wv[i] = *(const float4*)(W + (size_t)(o0 + r) * NK + kb + c4 * 4);
        }

        __syncthreads();

        #pragma unroll
        for (int i = 0; i < 4; ++i) {
            const int c = tid + 512 * i;
            const int r = c >> 4, c16 = c & 15;
            const int byte = (r * 256 + c16 * 16) ^ ((r & 7) << 4);
            *(ushort8v*)((char*)As + byte) = av[i];
        }
        #pragma unroll
        for (int i = 0; i < 4; ++i) {
            const int c = tid + 512 * i;
            const int r = c >> 5, c4 = c & 31;
            ushort4v bv = { f2bf(wv[i].x), f2bf(wv[i].y), f2bf(wv[i].z), f2bf(wv[i].w) };
            const int byte = (r * 256 + c4 * 8) ^ ((r & 7) << 4);
            *(ushort4v*)((char*)Bs + byte) = bv;
        }

        __syncthreads();

        #pragma unroll
        for (int kk = 0; kk < BK2; kk += 32) {
            short8 af[2], bf[2];
            #pragma unroll
            for (int mf = 0; mf < 2; ++mf) {
                const int r = wm * 32 + mf * 16 + lrow;
                const int byte = (r * 256 + (kk + lgrp * 8) * 2) ^ ((r & 7) << 4);
                af[mf] = *(const short8*)((const char*)As + byte);
            }
            #pragma unroll
            for (int nf = 0; nf < 2; ++nf) {
                const int r = wn * 32 + nf * 16 + lrow;
                const int byte = (r * 256 + (kk + lgrp * 8) * 2) ^ ((r & 7) << 4);
                bf[nf] = *(const short8*)((const char*)Bs + byte);
            }
            #pragma unroll
            for (int mf = 0; mf < 2; ++mf)
                #pragma unroll
                for (int nf = 0; nf < 2; ++nf)
                    acc[mf][nf] = __builtin_amdgcn_mfma_f32_16x16x32_bf16(
                        af[mf], bf[nf], acc[mf][nf], 0, 0, 0);
        }
    }

    float* pbase = part + (size_t)kz * NB * NO;
    #pragma unroll
    for (int mf = 0; mf < 2; ++mf) {
        #pragma unroll
        for (int nf = 0; nf < 2; ++nf) {
            const int o = o0 + wn * 32 + nf * 16 + lrow;
            #pragma unroll
            for (int reg = 0; reg < 4; ++reg) {
                const int m = wm * 32 + mf * 16 + lgrp * 4 + reg;
                pbase[(size_t)m * NO + o] = acc[mf][nf][reg];
            }
        }
    }
}

// ---------------------------------------------------------------------------
// k3: out[b][o] = bias[o] + sum_z part[z][b][o]
// ---------------------------------------------------------------------------
__global__ __launch_bounds__(256) void k3_reduce(
    const float* __restrict__ part, const float* __restrict__ bias,
    float* __restrict__ out)
{
    const int i = (blockIdx.x * 256 + threadIdx.x) * 4;
    float4 v = *(const float4*)(bias + (i & (NO - 1)));
    #pragma unroll
    for (int z = 0; z < KSPLIT; ++z) {
        float4 p = *(const float4*)(part + (size_t)z * NB * NO + i);
        v.x += p.x; v.y += p.y; v.z += p.z; v.w += p.w;
    }
    *(float4*)(out + i) = v;
}

extern "C" void kernel_launch(void* const* d_in, const int* in_sizes, int n_in,
                              void* d_out, int out_size, void* d_ws, size_t ws_size,
                              hipStream_t stream)
{
    const float* fillers = (const float*)d_in[0];
    const float* roles   = (const float*)d_in[1];
    const int*   lengths = (const int*)d_in[2];
    const float* W       = (const float*)d_in[3];
    const float* bias    = (const float*)d_in[4];
    float* out = (float*)d_out;

    // ws: [tensor bf16 4.19MB][parts bf16 16.8MB == overlaid part f32 16.8MB]
    unsigned short* tensor = (unsigned short*)d_ws;
    unsigned short* parts  = tensor + (size_t)NB * NK;   // k1 out, k1b in
    float*          part   = (float*)parts;              // k2 out, k3 in (disjoint lifetime)

    k1_mfma<<<NB * 8, 512, 0, stream>>>(fillers, roles, lengths, parts);
    k1b_reduce<<<(NB * NK / 8) / 256, 256, 0, stream>>>(parts, tensor);
    dim3 g2(NO / BN2, KSPLIT);   // (16, 32)
    k2_mfma<<<g2, 512, 0, stream>>>(tensor, W, part);
    k3_reduce<<<(NB * NO) / 1024, 256, 0, stream>>>(part, bias, out);
}

// Round 5
// 55.254 us; speedup vs baseline: 2.8864x; 1.2991x over previous
//
#include <hip/hip_runtime.h>
#include <hip/hip_bf16.h>

#define NB 128
#define NS 1024
#define NE 256
#define NR 64
#define NO 1024
#define NK (NE*NR)   // 16384

typedef __attribute__((ext_vector_type(8))) short short8;          // MFMA A/B frag (8 bf16)
typedef __attribute__((ext_vector_type(4))) float float4v;         // MFMA C/D frag
typedef __attribute__((ext_vector_type(4))) unsigned short ushort4v;
typedef __attribute__((ext_vector_type(8))) unsigned short ushort8v;

static __device__ inline unsigned short f2bf(float x) {
    union { float f; unsigned u; } v; v.f = x;
    unsigned r = v.u + 0x7fffu + ((v.u >> 16) & 1u);   // RNE
    return (unsigned short)(r >> 16);
}
static __device__ inline float bf2f(unsigned short h) {
    union { unsigned u; float f; } v; v.u = ((unsigned)h) << 16;
    return v.f;
}
// hardware RNE pair-convert; compiler fuses to v_cvt_pk_bf16_f32
static __device__ inline unsigned pk(float lo, float hi) {
    union { __hip_bfloat162 h2; unsigned u; } v;
    v.h2.x = __float2bfloat16(lo);
    v.h2.y = __float2bfloat16(hi);
    return v.u;
}

// ---------------------------------------------------------------------------
// k1: parts[ch][b][e][r] = sum_{s-pairs p == ch (mod 4), s<len} F[b][s][e]*R[b][s][r]
// LDS-FREE: each wave independently computes a 32e x 64r tile, loading MFMA
// fragments straight from global (lane l -> column e0+(l&15): lanes 0-15 are
// consecutive floats of one s-row = coalesced 64B segments). No barriers,
// no vmcnt(0) drain per step; 48 outstanding loads/wave hide latency.
// grid = NB*4 (s-chunks interleaved by pair), 512 threads = 8 waves (e-tiles).
// k (0..2*count) -> s = 128*t + 32*lgrp + 8*(j>>1) + (j&1) + 2*ch.
// ---------------------------------------------------------------------------
#define NCH 4

__global__ __launch_bounds__(512, 4) void k1_mfma(
    const float* __restrict__ fillers, const float* __restrict__ roles,
    const int* __restrict__ lengths, unsigned short* __restrict__ parts)
{
    const int bid = blockIdx.x;
    const int b   = bid >> 2;
    const int ch  = bid & 3;
    const int len = lengths[b];
    const int tid = threadIdx.x;

    const int lane = tid & 63;
    const int wid  = tid >> 6;      // 0..7 : e-tile of 32
    const int lrow = lane & 15;
    const int lgrp = lane >> 4;     // 0..3 : k-group

    const int e0 = wid * 32;

    // pairs p = ch + 4*q, p < P = ceil(len/2); count pairs -> 2*count k's
    const int P      = (len + 1) >> 1;
    const int count  = (P > ch) ? ((P - ch + 3) >> 2) : 0;
    const int nsteps = (count + 15) >> 4;    // <= 8

    float4v acc[2][4];   // [mf (16e)][nf (16r)]
    #pragma unroll
    for (int i = 0; i < 2; ++i)
        #pragma unroll
        for (int j = 0; j < 4; ++j)
            acc[i][j] = (float4v){0.f, 0.f, 0.f, 0.f};

    const float* fb = fillers + (size_t)b * NS * NE;
    const float* rb = roles   + (size_t)b * NS * NR;

    for (int t = 0; t < nsteps; ++t) {
        const int sbase = 128 * t + 32 * lgrp + 2 * ch;   // per-lane-group s base
        const int shi   = 128 * t + 121 + 2 * ch;         // max s this step (lgrp=3,j=7)

        float a0[8], a1[8], b0[8], b1[8], b2[8], b3[8];
        #pragma unroll
        for (int j = 0; j < 8; ++j) {
            const int s = sbase + ((j >> 1) << 3) + (j & 1);   // off = {0,1,8,9,16,17,24,25}
            const float* fr = fb + (size_t)s * NE;
            const float* rr = rb + (size_t)s * NR;
            a0[j] = fr[e0 + lrow];
            a1[j] = fr[e0 + 16 + lrow];
            b0[j] = rr[lrow];
            b1[j] = rr[16 + lrow];
            b2[j] = rr[32 + lrow];
            b3[j] = rr[48 + lrow];
        }

        if (shi >= len) {   // boundary step only (wave-uniform branch)
            #pragma unroll
            for (int j = 0; j < 8; ++j) {
                const int s = sbase + ((j >> 1) << 3) + (j & 1);
                const bool v = (s < len);
                a0[j] = v ? a0[j] : 0.f;  a1[j] = v ? a1[j] : 0.f;
                b0[j] = v ? b0[j] : 0.f;  b1[j] = v ? b1[j] : 0.f;
                b2[j] = v ? b2[j] : 0.f;  b3[j] = v ? b3[j] : 0.f;
            }
        }

        union { unsigned u[4]; short8 s8; } af[2], bf[4];
        #pragma unroll
        for (int jj = 0; jj < 4; ++jj) {
            af[0].u[jj] = pk(a0[2*jj], a0[2*jj+1]);
            af[1].u[jj] = pk(a1[2*jj], a1[2*jj+1]);
            bf[0].u[jj] = pk(b0[2*jj], b0[2*jj+1]);
            bf[1].u[jj] = pk(b1[2*jj], b1[2*jj+1]);
            bf[2].u[jj] = pk(b2[2*jj], b2[2*jj+1]);
            bf[3].u[jj] = pk(b3[2*jj], b3[2*jj+1]);
        }

        #pragma unroll
        for (int mf = 0; mf < 2; ++mf)
            #pragma unroll
            for (int nf = 0; nf < 4; ++nf)
                acc[mf][nf] = __builtin_amdgcn_mfma_f32_16x16x32_bf16(
                    af[mf].s8, bf[nf].s8, acc[mf][nf], 0, 0, 0);
    }

    // epilogue: C/D layout col=lane&15 (r), row=(lane>>4)*4+reg (e)
    unsigned short* pp = parts + (size_t)(ch * NB + b) * NK;
    #pragma unroll
    for (int mf = 0; mf < 2; ++mf) {
        #pragma unroll
        for (int nf = 0; nf < 4; ++nf) {
            const int r = nf * 16 + lrow;
            #pragma unroll
            for (int reg = 0; reg < 4; ++reg) {
                const int e = e0 + mf * 16 + lgrp * 4 + reg;
                pp[(size_t)e * NR + r] = f2bf(acc[mf][nf][reg]);
            }
        }
    }
}

// ---------------------------------------------------------------------------
// k1b: tensor[i] = bf16( sum_ch parts[ch][i] )
// ---------------------------------------------------------------------------
__global__ __launch_bounds__(256) void k1b_reduce(
    const unsigned short* __restrict__ parts, unsigned short* __restrict__ tensor)
{
    const size_t i = ((size_t)blockIdx.x * 256 + threadIdx.x) * 8;
    float s[8] = {0.f,0.f,0.f,0.f,0.f,0.f,0.f,0.f};
    #pragma unroll
    for (int ch = 0; ch < NCH; ++ch) {
        ushort8v v = *(const ushort8v*)(parts + (size_t)ch * NB * NK + i);
        #pragma unroll
        for (int j = 0; j < 8; ++j)
            s[j] += bf2f(v[j]);
    }
    ushort8v o;
    #pragma unroll
    for (int j = 0; j < 8; ++j)
        o[j] = f2bf(s[j]);
    *(ushort8v*)(tensor + i) = o;
}

// ---------------------------------------------------------------------------
// k2: part[kz][b][o] = sum_{k in chunk kz} T[b][k] * W[o][k]
// BM = 128 (= NB, W read once), BN = 64, BK = 128, KSPLIT = 32.
// ---------------------------------------------------------------------------
#define BN2 64
#define BK2 128
#define KSPLIT 32
#define KC2 (NK/KSPLIT)   // 512

__global__ __launch_bounds__(512) void k2_mfma(
    const unsigned short* __restrict__ A,   // tensor bf16 [NB][NK]
    const float* __restrict__ W,            // [NO][NK]
    float* __restrict__ part)               // [KSPLIT][NB][NO]
{
    __shared__ unsigned short As[128 * BK2];  // 32 KB, XOR-swizzled 256B rows
    __shared__ unsigned short Bs[BN2 * BK2];  // 16 KB

    const int o0   = blockIdx.x * BN2;
    const int kz   = blockIdx.y;
    const int tid  = threadIdx.x;
    const int lane = tid & 63;
    const int wid  = tid >> 6;
    const int wm   = wid >> 1;   // 0..3
    const int wn   = wid & 1;    // 0..1
    const int lrow = lane & 15;
    const int lgrp = lane >> 4;

    float4v acc[2][2];
    #pragma unroll
    for (int i = 0; i < 2; ++i)
        #pragma unroll
        for (int j = 0; j < 2; ++j)
            acc[i][j] = (float4v){0.f, 0.f, 0.f, 0.f};

    for (int step = 0; step < KC2 / BK2; ++step) {   // 4
        const int kb = kz * KC2 + step * BK2;

        ushort8v av[4];
        #pragma unroll
        for (int i = 0; i < 4; ++i) {
            const int c = tid + 512 * i;           // 0..2047
            const int r = c >> 4, c16 = c & 15;    // r 0..127
            av[i] = *(const ushort8v*)(A + (size_t)r * NK + kb + c16 * 8);
        }
        float4 wv[4];
        #pragma unroll
        for (int i = 0; i < 4; ++i) {
            const int c = tid + 512 * i;
            const int r = c >> 5, c4 = c & 31;     // r 0..63
            wv[i] = *(const float4*)(W + (size_t)(o0 + r) * NK + kb + c4 * 4);
        }

        __syncthreads();

        #pragma unroll
        for (int i = 0; i < 4; ++i) {
            const int c = tid + 512 * i;
            const int r = c >> 4, c16 = c & 15;
            const int byte = (r * 256 + c16 * 16) ^ ((r & 7) << 4);
            *(ushort8v*)((char*)As + byte) = av[i];
        }
        #pragma unroll
        for (int i = 0; i < 4; ++i) {
            const int c = tid + 512 * i;
            const int r = c >> 5, c4 = c & 31;
            ushort4v bv = { f2bf(wv[i].x), f2bf(wv[i].y), f2bf(wv[i].z), f2bf(wv[i].w) };
            const int byte = (r * 256 + c4 * 8) ^ ((r & 7) << 4);
            *(ushort4v*)((char*)Bs + byte) = bv;
        }

        __syncthreads();

        #pragma unroll
        for (int kk = 0; kk < BK2; kk += 32) {
            short8 af[2], bf[2];
            #pragma unroll
            for (int mf = 0; mf < 2; ++mf) {
                const int r = wm * 32 + mf * 16 + lrow;
                const int byte = (r * 256 + (kk + lgrp * 8) * 2) ^ ((r & 7) << 4);
                af[mf] = *(const short8*)((const char*)As + byte);
            }
            #pragma unroll
            for (int nf = 0; nf < 2; ++nf) {
                const int r = wn * 32 + nf * 16 + lrow;
                const int byte = (r * 256 + (kk + lgrp * 8) * 2) ^ ((r & 7) << 4);
                bf[nf] = *(const short8*)((const char*)Bs + byte);
            }
            #pragma unroll
            for (int mf = 0; mf < 2; ++mf)
                #pragma unroll
                for (int nf = 0; nf < 2; ++nf)
                    acc[mf][nf] = __builtin_amdgcn_mfma_f32_16x16x32_bf16(
                        af[mf], bf[nf], acc[mf][nf], 0, 0, 0);
        }
    }

    float* pbase = part + (size_t)kz * NB * NO;
    #pragma unroll
    for (int mf = 0; mf < 2; ++mf) {
        #pragma unroll
        for (int nf = 0; nf < 2; ++nf) {
            const int o = o0 + wn * 32 + nf * 16 + lrow;
            #pragma unroll
            for (int reg = 0; reg < 4; ++reg) {
                const int m = wm * 32 + mf * 16 + lgrp * 4 + reg;
                pbase[(size_t)m * NO + o] = acc[mf][nf][reg];
            }
        }
    }
}

// ---------------------------------------------------------------------------
// k3: out[b][o] = bias[o] + sum_z part[z][b][o]
// ---------------------------------------------------------------------------
__global__ __launch_bounds__(256) void k3_reduce(
    const float* __restrict__ part, const float* __restrict__ bias,
    float* __restrict__ out)
{
    const int i = (blockIdx.x * 256 + threadIdx.x) * 4;
    float4 v = *(const float4*)(bias + (i & (NO - 1)));
    #pragma unroll
    for (int z = 0; z < KSPLIT; ++z) {
        float4 p = *(const float4*)(part + (size_t)z * NB * NO + i);
        v.x += p.x; v.y += p.y; v.z += p.z; v.w += p.w;
    }
    *(float4*)(out + i) = v;
}

extern "C" void kernel_launch(void* const* d_in, const int* in_sizes, int n_in,
                              void* d_out, int out_size, void* d_ws, size_t ws_size,
                              hipStream_t stream)
{
    const float* fillers = (const float*)d_in[0];
    const float* roles   = (const float*)d_in[1];
    const int*   lengths = (const int*)d_in[2];
    const float* W       = (const float*)d_in[3];
    const float* bias    = (const float*)d_in[4];
    float* out = (float*)d_out;

    // ws: [tensor bf16 4.19MB][parts bf16 16.8MB == overlaid part f32 16.8MB]
    unsigned short* tensor = (unsigned short*)d_ws;
    unsigned short* parts  = tensor + (size_t)NB * NK;   // k1 out, k1b in
    float*          part   = (float*)parts;              // k2 out, k3 in (disjoint lifetime)

    k1_mfma<<<NB * NCH, 512, 0, stream>>>(fillers, roles, lengths, parts);
    k1b_reduce<<<(NB * NK / 8) / 256, 256, 0, stream>>>(parts, tensor);
    dim3 g2(NO / BN2, KSPLIT);   // (16, 32)
    k2_mfma<<<g2, 512, 0, stream>>>(tensor, W, part);
    k3_reduce<<<(NB * NO) / 1024, 256, 0, stream>>>(part, bias, out);
}